// Round 12
// baseline (300.833 us; speedup 1.0000x reference)
//
#include <hip/hip_runtime.h>
#include <stdint.h>
#include <stddef.h>

typedef __bf16 bf16_t;
typedef bf16_t bf16x4 __attribute__((ext_vector_type(4)));
typedef bf16_t bf16x8 __attribute__((ext_vector_type(8)));
typedef float  f32x4  __attribute__((ext_vector_type(4)));
typedef _Float16 f16_t;
typedef f16_t f16x2 __attribute__((ext_vector_type(2)));
typedef f16_t f16x4 __attribute__((ext_vector_type(4)));
typedef __fp16 fp16x2_raw __attribute__((ext_vector_type(2)));   // cvt_pkrtz native type

__device__ __forceinline__ f16x2 pkrtz(float a, float b) {
    fp16x2_raw r = __builtin_amdgcn_cvt_pkrtz(a, b);
    union { fp16x2_raw r; f16x2 h; } u;
    u.r = r;
    return u.h;
}

#define MFMA_BF16_K32(a, b, c) __builtin_amdgcn_mfma_f32_16x16x32_bf16(a, b, c, 0, 0, 0)
#define MFMA_F16_K16(a, b, c)  __builtin_amdgcn_mfma_f32_16x16x16f16(a, b, c, 0, 0, 0)

// ---------------------------------------------------------------- helpers
__device__ __forceinline__ void gload_lds16(const void* g, void* l) {
    __builtin_amdgcn_global_load_lds(
        (const __attribute__((address_space(1))) void*)g,
        (__attribute__((address_space(3))) void*)l,
        16, 0, 0);
}

// ---------------------------------------------------------------- fused fp32 -> bf16 casts
#define NX 1572864           // x  float4 count
#define NWA 442368           // Wa float4 count
#define NWP 147456           // Wp float4 count
__global__ void cvt_all(const float* __restrict__ x, const float* __restrict__ Wa,
                        const float* __restrict__ Wp, bf16_t* __restrict__ xb,
                        bf16_t* __restrict__ Wab, bf16_t* __restrict__ Wpb) {
    int i = blockIdx.x * blockDim.x + threadIdx.x;
    const float4* src; bf16_t* dst; int j;
    if (i < NX)            { src = (const float4*)x;  dst = xb;  j = i; }
    else if (i < NX + NWA) { src = (const float4*)Wa; dst = Wab; j = i - NX; }
    else                   { src = (const float4*)Wp; dst = Wpb; j = i - NX - NWA; }
    float4 f = src[j];
    bf16x4 o = { (bf16_t)f.x, (bf16_t)f.y, (bf16_t)f.z, (bf16_t)f.w };
    ((bf16x4*)dst)[j] = o;
}

// ---------------------------------------------------------------- GEMM main loop
template <int KDIM>
__device__ __forceinline__ void gemm_mainloop(
    const bf16_t* __restrict__ A, const bf16_t* __restrict__ Bt,
    bf16_t* As, bf16_t* Bs, int m0, int n0, int wave, int lane, f32x4 acc[4][4])
{
    const int quad = lane >> 4, l15 = lane & 15;
    const int wm = ((wave >> 1) << 6), wn = ((wave & 1) << 6);

    const int srow = (wave << 4) + (lane >> 2);                 // 0..63
    const int sw   = (((lane & 3) ^ ((srow >> 1) & 3)) << 3);   // swizzled elem offset
    const bf16_t* gA = A  + (size_t)(m0 + srow) * KDIM + sw;
    const bf16_t* gB = Bt + (size_t)(n0 + srow) * KDIM + sw;
    bf16_t* lA0 = As + wave * 512;
    bf16_t* lA1 = As + 2048 + wave * 512;
    bf16_t* lB0 = Bs + wave * 512;
    bf16_t* lB1 = Bs + 2048 + wave * 512;

    const int xorv = ((quad ^ ((l15 >> 1) & 3)) << 3);

    for (int k0 = 0; k0 < KDIM; k0 += 32) {
        __syncthreads();
        gload_lds16(gA + k0,                       lA0);
        gload_lds16(gA + (size_t)64 * KDIM + k0,   lA1);
        gload_lds16(gB + k0,                       lB0);
        gload_lds16(gB + (size_t)64 * KDIM + k0,   lB1);
        __syncthreads();

        bf16x8 af[4], bfr[4];
#pragma unroll
        for (int t = 0; t < 4; t++) {
            af[t]  = *(const bf16x8*)(As + (wm + t * 16 + l15) * 32 + xorv);
            bfr[t] = *(const bf16x8*)(Bs + (wn + t * 16 + l15) * 32 + xorv);
        }
#pragma unroll
        for (int mt = 0; mt < 4; mt++)
#pragma unroll
            for (int nt = 0; nt < 4; nt++)
                acc[mt][nt] = MFMA_BF16_K32(af[mt], bfr[nt], acc[mt][nt]);
    }
}

// ---------------------------------------------------------------- QKV projection
// SWAPPED: C^T = W_attn . x^T  ->  C rows (quad*4+r) are FEATURES, cols are
// tokens. q/k stores become bf16x4 along D; V^T stores stay scalar (1/3 of
// outputs, was the only vectorized one before — net 2/3 vectorized).
__global__ __launch_bounds__(256) void gemm_qkv(
    const bf16_t* __restrict__ Wab, // [2304,768] (A operand now)
    const bf16_t* __restrict__ xb,  // [8192,768] (Bt operand now)
    const float* __restrict__ bias, // [2304]
    bf16_t* __restrict__ qo, bf16_t* __restrict__ ko, f16_t* __restrict__ vo)
{
    __shared__ bf16_t As[128 * 32];
    __shared__ bf16_t Bs[128 * 32];
    const int tid = threadIdx.x, wave = tid >> 6, lane = tid & 63;
    const int quad = lane >> 4, l15 = lane & 15;
    const int m0 = blockIdx.x * 128;   // feature tile (0..2303)
    const int n0 = blockIdx.y * 128;   // token tile   (0..8191)
    f32x4 acc[4][4] = {};
    gemm_mainloop<768>(Wab, xb, As, Bs, m0, n0, wave, lane, acc);

    const int wm = ((wave >> 1) << 6), wn = ((wave & 1) << 6);
#pragma unroll
    for (int nt = 0; nt < 4; nt++) {
        const int tok = n0 + wn + nt * 16 + l15;    // 0..8191
        const int b = tok >> 12, tt = tok & 4095;
#pragma unroll
        for (int mt = 0; mt < 4; mt++) {
            const int f0 = m0 + wm + mt * 16 + quad * 4;   // feature, mult of 4
            const float4 bi = *(const float4*)(bias + f0);
            const int which = f0 / 768;
            const int rem = f0 - which * 768;
            const int h = rem >> 6, d0 = rem & 63;
            const float v0 = acc[mt][nt][0] + bi.x, v1 = acc[mt][nt][1] + bi.y;
            const float v2 = acc[mt][nt][2] + bi.z, v3 = acc[mt][nt][3] + bi.w;
            if (which < 2) {
                bf16_t* dst = (which == 0) ? qo : ko;
                bf16x4 ov = { (bf16_t)v0, (bf16_t)v1, (bf16_t)v2, (bf16_t)v3 };
                *(bf16x4*)(dst + ((size_t)(b * 12 + h) * 4096 + tt) * 64 + d0) = ov;
            } else {
                f16_t* vd = vo + ((size_t)(b * 12 + h) * 64 + d0) * 4096 + tt;
                vd[0]         = (f16_t)v0;
                vd[4096]      = (f16_t)v1;
                vd[2 * 4096]  = (f16_t)v2;
                vd[3 * 4096]  = (f16_t)v3;
            }
        }
    }
}

// ---------------------------------------------------------------- output projection
// SWAPPED: C^T = W_proj . y^T -> float4 stores along the feature dim.
__global__ __launch_bounds__(256) void gemm_proj(
    const bf16_t* __restrict__ Wpb, // [768,768] (A operand now)
    const bf16_t* __restrict__ yb,  // [8192,768] (Bt operand now)
    const float* __restrict__ bias, // [768]
    float* __restrict__ out)        // [8192,768] fp32
{
    __shared__ bf16_t As[128 * 32];
    __shared__ bf16_t Bs[128 * 32];
    const int tid = threadIdx.x, wave = tid >> 6, lane = tid & 63;
    const int quad = lane >> 4, l15 = lane & 15;
    const int m0 = blockIdx.x * 128;   // feature tile (0..767)
    const int n0 = blockIdx.y * 128;   // token tile
    f32x4 acc[4][4] = {};
    gemm_mainloop<768>(Wpb, yb, As, Bs, m0, n0, wave, lane, acc);

    const int wm = ((wave >> 1) << 6), wn = ((wave & 1) << 6);
#pragma unroll
    for (int nt = 0; nt < 4; nt++) {
        const int tok = n0 + wn + nt * 16 + l15;
#pragma unroll
        for (int mt = 0; mt < 4; mt++) {
            const int f0 = m0 + wm + mt * 16 + quad * 4;
            const float4 bi = *(const float4*)(bias + f0);
            float4 o = { acc[mt][nt][0] + bi.x, acc[mt][nt][1] + bi.y,
                         acc[mt][nt][2] + bi.z, acc[mt][nt][3] + bi.w };
            *(float4*)(out + (size_t)tok * 768 + f0) = o;
        }
    }
}

// ---------------------------------------------------------------- flash attention v12
// r11 inner loop + TRUE depth-2 pipeline: 3 statically-distinct LDS buffers
// (alias-provable -> no spurious compiler waits), 3-phase-unrolled loop, and
// raw `s_waitcnt vmcnt(4)` + `s_barrier` builtins instead of __syncthreads —
// waits only for the OLDEST stage; the newest prefetch stays in flight across
// the barrier (the AITER fine-vmcnt pattern the m97 2-barrier loop can't do).
// stage() = 4 global_load_lds instrs -> vmcnt(4) == "previous stage landed".
#define QSCALE 0.1803368801f   // log2(e)/8
#define WAIT_VM4 0x0F74        // vmcnt=4, expcnt=7, lgkmcnt=15 (no wait)
#define WAIT_VM0 0x0F70        // vmcnt=0 drain
__global__ __launch_bounds__(256, 3) void attn_fwd(
    const bf16_t* __restrict__ qg, const bf16_t* __restrict__ kg,
    const f16_t* __restrict__ vtg, bf16_t* __restrict__ y) // y [B,T,C] bf16
{
    // statically distinct staging buffers (8KB each)
    __shared__ __align__(16) bf16_t K0s[4096], K1s[4096], K2s[4096];
    __shared__ __align__(16) f16_t  V0s[4096], V1s[4096], V2s[4096];
    // epilogue scratch (separate; total LDS 48KB + 2.3KB)
    __shared__ __align__(16) float  Psr[256];
    __shared__ float PsT[64];
    float* RedA = (float*)K0s;                  // 17408B overlay (K0s+K1s+part K2s)
    float* RedB = (float*)(((char*)K0s) + 17408);

    const int tid = threadIdx.x, wave = tid >> 6, lane = tid & 63;
    const int quad = lane >> 4, l15 = lane & 15;

    const int blk = blockIdx.x;            // 0..1535
    const int xcd = blk & 7;
    const int idx = blk >> 3;              // 0..191
    const int hl  = idx % 3;
    const int qt  = idx / 3;               // 0..63
    const int bh  = xcd * 3 + hl;          // 0..23
    const int b = bh / 12, h = bh - b * 12;
    const size_t base = (size_t)bh * 4096 * 64;
    const bf16_t* kgt = kg + base;
    const f16_t*  vgt = vtg + base;

    // Q fragments for all 4 qrow-chunks (B-operand: n=l15, k=quad*8+j), *log2e/8
    bf16x8 qf[4][2];
#pragma unroll
    for (int qc = 0; qc < 4; qc++) {
        const int qrow = qt * 64 + qc * 16 + l15;
        qf[qc][0] = *(const bf16x8*)(qg + base + (size_t)qrow * 64 + quad * 8);
        qf[qc][1] = *(const bf16x8*)(qg + base + (size_t)qrow * 64 + 32 + quad * 8);
#pragma unroll
        for (int j = 0; j < 8; j++) {
            qf[qc][0][j] = (bf16_t)((float)qf[qc][0][j] * QSCALE);
            qf[qc][1][j] = (bf16_t)((float)qf[qc][1][j] * QSCALE);
        }
    }

    f32x4 O[4][4] = {};      // O^T partial: [dt][qc]; dim=dt*16+quad*4+r, qrow=qc*16+l15
    float psum[4] = {};      // per-lane partial row sums (qrow = qc*16+l15)
    const f16x2 one2 = { (f16_t)1.0f, (f16_t)1.0f };

    // staging: 8 lanes per 128B row, 16B chunks XOR-swizzled on row&7
    const int srow8 = tid >> 3;                  // 0..31 (+32 for i=1)
    const int sc8   = (tid & 7) ^ (srow8 & 7);
    const int l8 = l15 & 7;
    const int w16 = wave << 4;
    const int ksoff = (quad ^ l8) << 3;                          // K frag slot (elems)
    const int vslot = ((wave << 1) | (quad >> 1)) ^ l8;          // V frag 16B slot
    const int q0off = (quad & 1) * 8;

    auto stageT = [&](int t, bf16_t* Kd, f16_t* Vd) {
        const bf16_t* kp = kgt + (size_t)t * 4096;
        const f16_t*  vp = vgt + t * 64;
#pragma unroll
        for (int i = 0; i < 2; i++) {
            gload_lds16(kp + (i * 32 + srow8) * 64 + sc8 * 8,           Kd + (i * 256 + tid) * 8);
            gload_lds16(vp + (size_t)(i * 32 + srow8) * 4096 + sc8 * 8, Vd + (i * 256 + tid) * 8);
        }
    };

    auto compute = [&](const bf16_t* ks, const f16_t* vs) {
        const bf16_t* kr = ks + (w16 + l15) * 64;
        bf16x8 kf0 = *(const bf16x8*)(kr + ksoff);
        bf16x8 kf1 = *(const bf16x8*)(kr + (ksoff ^ 32));
        f32x4 sc[4];
#pragma unroll
        for (int qc = 0; qc < 4; qc++) {
            f32x4 s = {};
            s = MFMA_BF16_K32(kf0, qf[qc][0], s);
            s = MFMA_BF16_K32(kf1, qf[qc][1], s);
            sc[qc] = s;
        }
        f16x4 pf[4];
#pragma unroll
        for (int qc = 0; qc < 4; qc++) {
            float e0 = __builtin_amdgcn_exp2f(sc[qc][0]);
            float e1 = __builtin_amdgcn_exp2f(sc[qc][1]);
            float e2 = __builtin_amdgcn_exp2f(sc[qc][2]);
            float e3 = __builtin_amdgcn_exp2f(sc[qc][3]);
            f16x2 lo = pkrtz(e0, e1);
            f16x2 hi = pkrtz(e2, e3);
            psum[qc] = __builtin_amdgcn_fdot2(lo, one2, psum[qc], false);
            psum[qc] = __builtin_amdgcn_fdot2(hi, one2, psum[qc], false);
            f16x4 p;
            *(f16x2*)&p = lo;
            *(((f16x2*)&p) + 1) = hi;
            pf[qc] = p;
        }
#pragma unroll
        for (int dt = 0; dt < 4; dt++) {
            const char* vr = (const char*)(vs + (dt * 16 + l15) * 64);
            f16x4 vf = *(const f16x4*)(vr + vslot * 16 + q0off);
#pragma unroll
            for (int qc = 0; qc < 4; qc++)
                O[dt][qc] = MFMA_F16_K16(vf, pf[qc], O[dt][qc]);
        }
    };

    // ---- pipelined K-loop: tiles 0..63, prefetch distance 2
    stageT(0, K0s, V0s);
    stageT(1, K1s, V1s);
    for (int t = 0; t < 63; t += 3) {
        __builtin_amdgcn_s_waitcnt(WAIT_VM4);   // stage(t) landed; stage(t+1) flying
        __builtin_amdgcn_s_barrier();
        compute(K0s, V0s);
        stageT(t + 2, K2s, V2s);

        __builtin_amdgcn_s_waitcnt(WAIT_VM4);
        __builtin_amdgcn_s_barrier();
        compute(K1s, V1s);
        stageT(t + 3, K0s, V0s);

        __builtin_amdgcn_s_waitcnt(WAIT_VM4);
        __builtin_amdgcn_s_barrier();
        compute(K2s, V2s);
        stageT(t + 4 < 64 ? t + 4 : 63, K1s, V1s);   // dummy re-stage at the end
    }
    __builtin_amdgcn_s_waitcnt(WAIT_VM0);       // drain (incl. dummies)
    __builtin_amdgcn_s_barrier();
    compute(K0s, V0s);                           // tile 63 (63%3==0)

    // ================= epilogue: reduce O & psum across the 4 key-split waves
#pragma unroll
    for (int qc = 0; qc < 4; qc++) {
        psum[qc] += __shfl_xor(psum[qc], 16, 64);
        psum[qc] += __shfl_xor(psum[qc], 32, 64);
    }
    __syncthreads();   // K-loop LDS quiesced (full drain); overlay safe
    if (wave == 2) {
#pragma unroll
        for (int dt = 0; dt < 4; dt++)
#pragma unroll
            for (int qc = 0; qc < 4; qc++)
                *(f32x4*)(RedA + (qc * 16 + l15) * 68 + dt * 16 + quad * 4) = O[dt][qc];
    } else if (wave == 3) {
#pragma unroll
        for (int dt = 0; dt < 4; dt++)
#pragma unroll
            for (int qc = 0; qc < 4; qc++)
                *(f32x4*)(RedB + (qc * 16 + l15) * 68 + dt * 16 + quad * 4) = O[dt][qc];
    }
    if (quad == 0) {
#pragma unroll
        for (int qc = 0; qc < 4; qc++) Psr[wave * 64 + qc * 16 + l15] = psum[qc];
    }
    __syncthreads();   // S2
    if (wave == 0) {
#pragma unroll
        for (int dt = 0; dt < 4; dt++)
#pragma unroll
            for (int qc = 0; qc < 4; qc++)
                O[dt][qc] += *(const f32x4*)(RedA + (qc * 16 + l15) * 68 + dt * 16 + quad * 4);
    } else if (wave == 1) {
#pragma unroll
        for (int dt = 0; dt < 4; dt++)
#pragma unroll
            for (int qc = 0; qc < 4; qc++)
                O[dt][qc] += *(const f32x4*)(RedB + (qc * 16 + l15) * 68 + dt * 16 + quad * 4);
    }
    __syncthreads();   // S3
    if (wave == 1) {
#pragma unroll
        for (int dt = 0; dt < 4; dt++)
#pragma unroll
            for (int qc = 0; qc < 4; qc++)
                *(f32x4*)(RedA + (qc * 16 + l15) * 68 + dt * 16 + quad * 4) = O[dt][qc];
    } else if (wave == 3) {
        PsT[lane] = Psr[lane] + Psr[64 + lane] + Psr[128 + lane] + Psr[192 + lane];
    }
    __syncthreads();   // S4
    if (wave == 0) {
#pragma unroll
        for (int qc = 0; qc < 4; qc++) {
            const float rcp = 1.0f / PsT[qc * 16 + l15];
            const int t = qt * 64 + qc * 16 + l15;
            bf16_t* yr = y + ((size_t)b * 4096 + t) * 768 + h * 64 + quad * 4;
#pragma unroll
            for (int dt = 0; dt < 4; dt++) {
                f32x4 o4 = O[dt][qc] +
                    *(const f32x4*)(RedA + (qc * 16 + l15) * 68 + dt * 16 + quad * 4);
                bf16x4 ov = { (bf16_t)(o4[0] * rcp), (bf16_t)(o4[1] * rcp),
                              (bf16_t)(o4[2] * rcp), (bf16_t)(o4[3] * rcp) };
                *(bf16x4*)(yr + dt * 16) = ov;
            }
        }
    }
}

// ---------------------------------------------------------------- launch
extern "C" void kernel_launch(void* const* d_in, const int* in_sizes, int n_in,
                              void* d_out, int out_size, void* d_ws, size_t ws_size,
                              hipStream_t stream) {
    const float* x  = (const float*)d_in[0]; // [2,4096,768]
    const float* Wa = (const float*)d_in[1]; // [2304,768]
    const float* ba = (const float*)d_in[2]; // [2304]
    const float* Wp = (const float*)d_in[3]; // [768,768]
    const float* bp = (const float*)d_in[4]; // [768]
    float* out = (float*)d_out;              // [2,4096,768]

    char* ws = (char*)d_ws;
    bf16_t* xb  = (bf16_t*)(ws);                 //  6291456 elts
    bf16_t* Wab = (bf16_t*)(ws + 12582912);      //  1769472
    bf16_t* Wpb = (bf16_t*)(ws + 16121856);      //   589824
    bf16_t* qb  = (bf16_t*)(ws + 17301504);      //  [B,H,T,D] bf16
    bf16_t* kb  = (bf16_t*)(ws + 29884416);      //  [B,H,T,D] bf16
    f16_t*  vtb = (f16_t*)(ws + 42467328);       //  [B,H,D,T] f16 (transposed)
    bf16_t* yb  = (bf16_t*)(ws + 55050240);      //  [B,T,C] bf16

    cvt_all<<<8448, 256, 0, stream>>>(x, Wa, Wp, xb, Wab, Wpb);
    gemm_qkv <<<dim3(18, 64), 256, 0, stream>>>(Wab, xb, ba, qb, kb, vtb);
    attn_fwd <<<1536, 256, 0, stream>>>(qb, kb, vtb, yb);
    gemm_proj<<<dim3( 6, 64), 256, 0, stream>>>(Wpb, yb, bp, out);
}

// Round 13
// 297.719 us; speedup vs baseline: 1.0105x; 1.0105x over previous
//
#include <hip/hip_runtime.h>
#include <stdint.h>
#include <stddef.h>

typedef __bf16 bf16_t;
typedef bf16_t bf16x4 __attribute__((ext_vector_type(4)));
typedef bf16_t bf16x8 __attribute__((ext_vector_type(8)));
typedef float  f32x4  __attribute__((ext_vector_type(4)));
typedef _Float16 f16_t;
typedef f16_t f16x2 __attribute__((ext_vector_type(2)));
typedef f16_t f16x4 __attribute__((ext_vector_type(4)));
typedef __fp16 fp16x2_raw __attribute__((ext_vector_type(2)));   // cvt_pkrtz native type

__device__ __forceinline__ f16x2 pkrtz(float a, float b) {
    fp16x2_raw r = __builtin_amdgcn_cvt_pkrtz(a, b);
    union { fp16x2_raw r; f16x2 h; } u;
    u.r = r;
    return u.h;
}

#define MFMA_BF16_K32(a, b, c) __builtin_amdgcn_mfma_f32_16x16x32_bf16(a, b, c, 0, 0, 0)
#define MFMA_F16_K16(a, b, c)  __builtin_amdgcn_mfma_f32_16x16x16f16(a, b, c, 0, 0, 0)

// ---------------------------------------------------------------- helpers
__device__ __forceinline__ void gload_lds16(const void* g, void* l) {
    __builtin_amdgcn_global_load_lds(
        (const __attribute__((address_space(1))) void*)g,
        (__attribute__((address_space(3))) void*)l,
        16, 0, 0);
}

// ---------------------------------------------------------------- fused fp32 -> bf16 casts
#define NX 1572864           // x  float4 count
#define NWA 442368           // Wa float4 count
#define NWP 147456           // Wp float4 count
__global__ void cvt_all(const float* __restrict__ x, const float* __restrict__ Wa,
                        const float* __restrict__ Wp, bf16_t* __restrict__ xb,
                        bf16_t* __restrict__ Wab, bf16_t* __restrict__ Wpb) {
    int i = blockIdx.x * blockDim.x + threadIdx.x;
    const float4* src; bf16_t* dst; int j;
    if (i < NX)            { src = (const float4*)x;  dst = xb;  j = i; }
    else if (i < NX + NWA) { src = (const float4*)Wa; dst = Wab; j = i - NX; }
    else                   { src = (const float4*)Wp; dst = Wpb; j = i - NX - NWA; }
    float4 f = src[j];
    bf16x4 o = { (bf16_t)f.x, (bf16_t)f.y, (bf16_t)f.z, (bf16_t)f.w };
    ((bf16x4*)dst)[j] = o;
}

// ---------------------------------------------------------------- GEMM main loop
template <int KDIM>
__device__ __forceinline__ void gemm_mainloop(
    const bf16_t* __restrict__ A, const bf16_t* __restrict__ Bt,
    bf16_t* As, bf16_t* Bs, int m0, int n0, int wave, int lane, f32x4 acc[4][4])
{
    const int quad = lane >> 4, l15 = lane & 15;
    const int wm = ((wave >> 1) << 6), wn = ((wave & 1) << 6);

    const int srow = (wave << 4) + (lane >> 2);                 // 0..63
    const int sw   = (((lane & 3) ^ ((srow >> 1) & 3)) << 3);   // swizzled elem offset
    const bf16_t* gA = A  + (size_t)(m0 + srow) * KDIM + sw;
    const bf16_t* gB = Bt + (size_t)(n0 + srow) * KDIM + sw;
    bf16_t* lA0 = As + wave * 512;
    bf16_t* lA1 = As + 2048 + wave * 512;
    bf16_t* lB0 = Bs + wave * 512;
    bf16_t* lB1 = Bs + 2048 + wave * 512;

    const int xorv = ((quad ^ ((l15 >> 1) & 3)) << 3);

    for (int k0 = 0; k0 < KDIM; k0 += 32) {
        __syncthreads();
        gload_lds16(gA + k0,                       lA0);
        gload_lds16(gA + (size_t)64 * KDIM + k0,   lA1);
        gload_lds16(gB + k0,                       lB0);
        gload_lds16(gB + (size_t)64 * KDIM + k0,   lB1);
        __syncthreads();

        bf16x8 af[4], bfr[4];
#pragma unroll
        for (int t = 0; t < 4; t++) {
            af[t]  = *(const bf16x8*)(As + (wm + t * 16 + l15) * 32 + xorv);
            bfr[t] = *(const bf16x8*)(Bs + (wn + t * 16 + l15) * 32 + xorv);
        }
#pragma unroll
        for (int mt = 0; mt < 4; mt++)
#pragma unroll
            for (int nt = 0; nt < 4; nt++)
                acc[mt][nt] = MFMA_BF16_K32(af[mt], bfr[nt], acc[mt][nt]);
    }
}

// ---------------------------------------------------------------- QKV projection
// C^T = W_attn . x^T  ->  C rows (quad*4+r) are FEATURES, cols are tokens.
__global__ __launch_bounds__(256) void gemm_qkv(
    const bf16_t* __restrict__ Wab, // [2304,768] (A operand)
    const bf16_t* __restrict__ xb,  // [8192,768] (Bt operand)
    const float* __restrict__ bias, // [2304]
    bf16_t* __restrict__ qo, bf16_t* __restrict__ ko, f16_t* __restrict__ vo)
{
    __shared__ bf16_t As[128 * 32];
    __shared__ bf16_t Bs[128 * 32];
    const int tid = threadIdx.x, wave = tid >> 6, lane = tid & 63;
    const int quad = lane >> 4, l15 = lane & 15;
    const int m0 = blockIdx.x * 128;   // feature tile (0..2303)
    const int n0 = blockIdx.y * 128;   // token tile   (0..8191)
    f32x4 acc[4][4] = {};
    gemm_mainloop<768>(Wab, xb, As, Bs, m0, n0, wave, lane, acc);

    const int wm = ((wave >> 1) << 6), wn = ((wave & 1) << 6);
#pragma unroll
    for (int nt = 0; nt < 4; nt++) {
        const int tok = n0 + wn + nt * 16 + l15;    // 0..8191
        const int b = tok >> 12, tt = tok & 4095;
#pragma unroll
        for (int mt = 0; mt < 4; mt++) {
            const int f0 = m0 + wm + mt * 16 + quad * 4;   // feature, mult of 4
            const float4 bi = *(const float4*)(bias + f0);
            const int which = f0 / 768;
            const int rem = f0 - which * 768;
            const int h = rem >> 6, d0 = rem & 63;
            const float v0 = acc[mt][nt][0] + bi.x, v1 = acc[mt][nt][1] + bi.y;
            const float v2 = acc[mt][nt][2] + bi.z, v3 = acc[mt][nt][3] + bi.w;
            if (which < 2) {
                bf16_t* dst = (which == 0) ? qo : ko;
                bf16x4 ov = { (bf16_t)v0, (bf16_t)v1, (bf16_t)v2, (bf16_t)v3 };
                *(bf16x4*)(dst + ((size_t)(b * 12 + h) * 4096 + tt) * 64 + d0) = ov;
            } else {
                f16_t* vd = vo + ((size_t)(b * 12 + h) * 64 + d0) * 4096 + tt;
                vd[0]         = (f16_t)v0;
                vd[4096]      = (f16_t)v1;
                vd[2 * 4096]  = (f16_t)v2;
                vd[3 * 4096]  = (f16_t)v3;
            }
        }
    }
}

// ---------------------------------------------------------------- output projection
__global__ __launch_bounds__(256) void gemm_proj(
    const bf16_t* __restrict__ Wpb, // [768,768] (A operand)
    const bf16_t* __restrict__ yb,  // [8192,768] (Bt operand)
    const float* __restrict__ bias, // [768]
    float* __restrict__ out)        // [8192,768] fp32
{
    __shared__ bf16_t As[128 * 32];
    __shared__ bf16_t Bs[128 * 32];
    const int tid = threadIdx.x, wave = tid >> 6, lane = tid & 63;
    const int quad = lane >> 4, l15 = lane & 15;
    const int m0 = blockIdx.x * 128;   // feature tile (0..767)
    const int n0 = blockIdx.y * 128;   // token tile
    f32x4 acc[4][4] = {};
    gemm_mainloop<768>(Wpb, yb, As, Bs, m0, n0, wave, lane, acc);

    const int wm = ((wave >> 1) << 6), wn = ((wave & 1) << 6);
#pragma unroll
    for (int nt = 0; nt < 4; nt++) {
        const int tok = n0 + wn + nt * 16 + l15;
#pragma unroll
        for (int mt = 0; mt < 4; mt++) {
            const int f0 = m0 + wm + mt * 16 + quad * 4;
            const float4 bi = *(const float4*)(bias + f0);
            float4 o = { acc[mt][nt][0] + bi.x, acc[mt][nt][1] + bi.y,
                         acc[mt][nt][2] + bi.z, acc[mt][nt][3] + bi.w };
            *(float4*)(out + (size_t)tok * 768 + f0) = o;
        }
    }
}

// ---------------------------------------------------------------- flash attention v13
// WAVE-PRIVATE staging, ZERO K-loop barriers. Key-split means wave w touches
// only K rows / V cols w*16..+15 of each tile -> no cross-wave sharing -> each
// wave stages its own 2KB K-slab (contiguous, 2 coalesced global_load_lds) and
// 2KB V-slab into a private 8KB LDS region, double-buffered, ordered by
// per-wave `s_waitcnt vmcnt(4)` (wait-oldest). Waves free-run and slip phase;
// TLP hides latency instead of a lockstep block pipeline (r5/r12 failures).
// r11's VALU diet kept. Epilogue (3 barriers) unchanged.
#define QSCALE 0.1803368801f   // log2(e)/8
#define WAIT_VM4 0x0F74        // vmcnt=4, expcnt/lgkmcnt no-wait
#define WAIT_VM0 0x0F70        // vmcnt=0
__global__ __launch_bounds__(256, 3) void attn_fwd(
    const bf16_t* __restrict__ qg, const bf16_t* __restrict__ kg,
    const f16_t* __restrict__ vtg, bf16_t* __restrict__ y) // y [B,T,C] bf16
{
    __shared__ __align__(16) char smem[36864];
    // per-wave staging region at smem + wave*8192:
    //   K0 [0,2048) | V0 [2048,4096) | K1 [4096,6144) | V1 [6144,8192)
    float* RedA = (float*)smem;                 // epilogue overlays
    float* RedB = (float*)(smem + 17408);
    float* Psr  = (float*)(smem + 34816);       // [4][64]
    float* PsT  = (float*)(smem + 35840);       // [64]

    const int tid = threadIdx.x, wave = tid >> 6, lane = tid & 63;
    const int quad = lane >> 4, l15 = lane & 15;

    const int blk = blockIdx.x;            // 0..1535
    const int xcd = blk & 7;
    const int idx = blk >> 3;              // 0..191
    const int hl  = idx % 3;
    const int qt  = idx / 3;               // 0..63
    const int bh  = xcd * 3 + hl;          // 0..23
    const int b = bh / 12, h = bh - b * 12;
    const size_t base = (size_t)bh * 4096 * 64;
    const bf16_t* kgt = kg + base;
    const f16_t*  vgt = vtg + base;

    char* wbase = smem + wave * 8192;
    bf16_t* K0w = (bf16_t*)(wbase);
    f16_t*  V0w = (f16_t*)(wbase + 2048);
    bf16_t* K1w = (bf16_t*)(wbase + 4096);
    f16_t*  V1w = (f16_t*)(wbase + 6144);

    // Q fragments for all 4 qrow-chunks (B-operand: n=l15, k=quad*8+j), *log2e/8
    bf16x8 qf[4][2];
#pragma unroll
    for (int qc = 0; qc < 4; qc++) {
        const int qrow = qt * 64 + qc * 16 + l15;
        qf[qc][0] = *(const bf16x8*)(qg + base + (size_t)qrow * 64 + quad * 8);
        qf[qc][1] = *(const bf16x8*)(qg + base + (size_t)qrow * 64 + 32 + quad * 8);
#pragma unroll
        for (int j = 0; j < 8; j++) {
            qf[qc][0][j] = (bf16_t)((float)qf[qc][0][j] * QSCALE);
            qf[qc][1][j] = (bf16_t)((float)qf[qc][1][j] * QSCALE);
        }
    }

    f32x4 O[4][4] = {};      // O^T partial: [dt][qc]; dim=dt*16+quad*4+r, qrow=qc*16+l15
    float psum[4] = {};      // per-lane partial row sums (qrow = qc*16+l15)
    const f16x2 one2 = { (f16_t)1.0f, (f16_t)1.0f };

    const int l8 = l15 & 7;
    const int w16 = wave << 4;
    const int ksoff = (quad ^ l8) << 3;          // K frag slot offset (elems)
    // staging lane addresses (wave-private slabs)
    const int krow = lane >> 3;                  // 0..7 (+8 for instr 2)
    const int kchk = (lane & 7) ^ krow;          // swizzled 16B chunk within 128B row
    const int vrow = lane >> 1;                  // 0..31 (+32)
    const int vhalf = (lane & 1) << 3;           // 0 or 8 f16

    auto stageT = [&](int t, bf16_t* Kd, f16_t* Vd) {
        const bf16_t* kp = kgt + (size_t)(t * 64 + w16) * 64;
        const f16_t*  vp = vgt + t * 64 + w16;
        gload_lds16(kp + krow * 64 + kchk * 8,               Kd);
        gload_lds16(kp + (8 + krow) * 64 + kchk * 8,         Kd + 512);
        gload_lds16(vp + (size_t)vrow * 4096 + vhalf,        Vd);
        gload_lds16(vp + (size_t)(32 + vrow) * 4096 + vhalf, Vd + 512);
    };

    auto compute = [&](const bf16_t* ks, const f16_t* vs) {
        // S^T (wave's 16 keys x 64 qrows): K local rows = l15
        const bf16_t* kr = ks + l15 * 64;
        bf16x8 kf0 = *(const bf16x8*)(kr + ksoff);
        bf16x8 kf1 = *(const bf16x8*)(kr + (ksoff ^ 32));
        f32x4 sc[4];
#pragma unroll
        for (int qc = 0; qc < 4; qc++) {
            f32x4 s = {};
            s = MFMA_BF16_K32(kf0, qf[qc][0], s);
            s = MFMA_BF16_K32(kf1, qf[qc][1], s);
            sc[qc] = s;
        }
        f16x4 pf[4];
#pragma unroll
        for (int qc = 0; qc < 4; qc++) {
            float e0 = __builtin_amdgcn_exp2f(sc[qc][0]);
            float e1 = __builtin_amdgcn_exp2f(sc[qc][1]);
            float e2 = __builtin_amdgcn_exp2f(sc[qc][2]);
            float e3 = __builtin_amdgcn_exp2f(sc[qc][3]);
            f16x2 lo = pkrtz(e0, e1);
            f16x2 hi = pkrtz(e2, e3);
            psum[qc] = __builtin_amdgcn_fdot2(lo, one2, psum[qc], false);
            psum[qc] = __builtin_amdgcn_fdot2(hi, one2, psum[qc], false);
            f16x4 p;
            *(f16x2*)&p = lo;
            *(((f16x2*)&p) + 1) = hi;
            pf[qc] = p;
        }
        // O^T += V^T P : V local row (dim) stride = 16 f16 (32B), keys quad*4..+3
#pragma unroll
        for (int dt = 0; dt < 4; dt++) {
            f16x4 vf = *(const f16x4*)(vs + (dt * 16 + l15) * 16 + quad * 4);
#pragma unroll
            for (int qc = 0; qc < 4; qc++)
                O[dt][qc] = MFMA_F16_K16(vf, pf[qc], O[dt][qc]);
        }
    };

    // ---- barrier-free double-buffered K-loop (per-wave vmcnt discipline)
    __builtin_amdgcn_s_waitcnt(WAIT_VM0);   // Q loads drained: clean vm counter
    stageT(0, K0w, V0w);
    stageT(1, K1w, V1w);
    for (int t = 0; t < 62; t += 2) {
        __builtin_amdgcn_s_waitcnt(WAIT_VM4);   // buf0's 4 loads landed
        compute(K0w, V0w);
        stageT(t + 2, K0w, V0w);
        __builtin_amdgcn_s_waitcnt(WAIT_VM4);   // buf1's 4 loads landed
        compute(K1w, V1w);
        stageT(t + 3, K1w, V1w);
    }
    __builtin_amdgcn_s_waitcnt(WAIT_VM4);
    compute(K0w, V0w);                           // tile 62
    __builtin_amdgcn_s_waitcnt(WAIT_VM0);
    compute(K1w, V1w);                           // tile 63

    // ================= epilogue: reduce O & psum across the 4 key-split waves
#pragma unroll
    for (int qc = 0; qc < 4; qc++) {
        psum[qc] += __shfl_xor(psum[qc], 16, 64);
        psum[qc] += __shfl_xor(psum[qc], 32, 64);
    }
    __syncthreads();   // all waves' K-loop LDS quiesced; overlay safe
    if (wave == 2) {
#pragma unroll
        for (int dt = 0; dt < 4; dt++)
#pragma unroll
            for (int qc = 0; qc < 4; qc++)
                *(f32x4*)(RedA + (qc * 16 + l15) * 68 + dt * 16 + quad * 4) = O[dt][qc];
    } else if (wave == 3) {
#pragma unroll
        for (int dt = 0; dt < 4; dt++)
#pragma unroll
            for (int qc = 0; qc < 4; qc++)
                *(f32x4*)(RedB + (qc * 16 + l15) * 68 + dt * 16 + quad * 4) = O[dt][qc];
    }
    if (quad == 0) {
#pragma unroll
        for (int qc = 0; qc < 4; qc++) Psr[wave * 64 + qc * 16 + l15] = psum[qc];
    }
    __syncthreads();   // S2
    if (wave == 0) {
#pragma unroll
        for (int dt = 0; dt < 4; dt++)
#pragma unroll
            for (int qc = 0; qc < 4; qc++)
                O[dt][qc] += *(const f32x4*)(RedA + (qc * 16 + l15) * 68 + dt * 16 + quad * 4);
    } else if (wave == 1) {
#pragma unroll
        for (int dt = 0; dt < 4; dt++)
#pragma unroll
            for (int qc = 0; qc < 4; qc++)
                O[dt][qc] += *(const f32x4*)(RedB + (qc * 16 + l15) * 68 + dt * 16 + quad * 4);
    }
    __syncthreads();   // S3
    if (wave == 1) {
#pragma unroll
        for (int dt = 0; dt < 4; dt++)
#pragma unroll
            for (int qc = 0; qc < 4; qc++)
                *(f32x4*)(RedA + (qc * 16 + l15) * 68 + dt * 16 + quad * 4) = O[dt][qc];
    } else if (wave == 3) {
        PsT[lane] = Psr[lane] + Psr[64 + lane] + Psr[128 + lane] + Psr[192 + lane];
    }
    __syncthreads();   // S4
    if (wave == 0) {
#pragma unroll
        for (int qc = 0; qc < 4; qc++) {
            const float rcp = 1.0f / PsT[qc * 16 + l15];
            const int t = qt * 64 + qc * 16 + l15;
            bf16_t* yr = y + ((size_t)b * 4096 + t) * 768 + h * 64 + quad * 4;
#pragma unroll
            for (int dt = 0; dt < 4; dt++) {
                f32x4 o4 = O[dt][qc] +
                    *(const f32x4*)(RedA + (qc * 16 + l15) * 68 + dt * 16 + quad * 4);
                bf16x4 ov = { (bf16_t)(o4[0] * rcp), (bf16_t)(o4[1] * rcp),
                              (bf16_t)(o4[2] * rcp), (bf16_t)(o4[3] * rcp) };
                *(bf16x4*)(yr + dt * 16) = ov;
            }
        }
    }
}

// ---------------------------------------------------------------- launch
extern "C" void kernel_launch(void* const* d_in, const int* in_sizes, int n_in,
                              void* d_out, int out_size, void* d_ws, size_t ws_size,
                              hipStream_t stream) {
    const float* x  = (const float*)d_in[0]; // [2,4096,768]
    const float* Wa = (const float*)d_in[1]; // [2304,768]
    const float* ba = (const float*)d_in[2]; // [2304]
    const float* Wp = (const float*)d_in[3]; // [768,768]
    const float* bp = (const float*)d_in[4]; // [768]
    float* out = (float*)d_out;              // [2,4096,768]

    char* ws = (char*)d_ws;
    bf16_t* xb  = (bf16_t*)(ws);                 //  6291456 elts
    bf16_t* Wab = (bf16_t*)(ws + 12582912);      //  1769472
    bf16_t* Wpb = (bf16_t*)(ws + 16121856);      //   589824
    bf16_t* qb  = (bf16_t*)(ws + 17301504);      //  [B,H,T,D] bf16
    bf16_t* kb  = (bf16_t*)(ws + 29884416);      //  [B,H,T,D] bf16
    f16_t*  vtb = (f16_t*)(ws + 42467328);       //  [B,H,D,T] f16 (transposed)
    bf16_t* yb  = (bf16_t*)(ws + 55050240);      //  [B,T,C] bf16

    cvt_all<<<8448, 256, 0, stream>>>(x, Wa, Wp, xb, Wab, Wpb);
    gemm_qkv <<<dim3(18, 64), 256, 0, stream>>>(Wab, xb, ba, qb, kb, vtb);
    attn_fwd <<<1536, 256, 0, stream>>>(qb, kb, vtb, yb);
    gemm_proj<<<dim3( 6, 64), 256, 0, stream>>>(Wpb, yb, bp, out);
}